// Round 2
// baseline (344.348 us; speedup 1.0000x reference)
//
#include <hip/hip_runtime.h>
#include <hip/hip_cooperative_groups.h>

namespace cg = cooperative_groups;

// B=4, T=2048, C=1024, H=64. fp32 in/out, bf16 MFMA internally.
// ws layout (u16 elements):
//   [0,        524288)  q  bf16  [b*2048+t][64]
//   [524288,  1048576)  k  bf16  [b*2048+t][64]
//   [1048576, 1572864)  vT bf16  [b][h][t]   (b*131072 + h*2048 + t)
//   [1572864, 1769472)  wT bf16  [sel][h][c] (sel*65536 + h*1024 + c)

typedef __attribute__((ext_vector_type(8))) short short8;
typedef __attribute__((ext_vector_type(4))) float f32x4;

#define NTOT 524288   // 8192*64
#define WT_OFF (3 * NTOT)

__device__ __forceinline__ unsigned short f2bf(float f) {
    unsigned int u = __builtin_bit_cast(unsigned int, f);
    return (unsigned short)((u + 0x7fffu + ((u >> 16) & 1u)) >> 16);
}

__device__ __forceinline__ short8 pack8(float4 a, float4 b) {
    short8 r;
    r[0] = (short)f2bf(a.x); r[1] = (short)f2bf(a.y);
    r[2] = (short)f2bf(a.z); r[3] = (short)f2bf(a.w);
    r[4] = (short)f2bf(b.x); r[5] = (short)f2bf(b.y);
    r[6] = (short)f2bf(b.z); r[7] = (short)f2bf(b.w);
    return r;
}

// ===========================================================================
// Fallback path: the three proven standalone kernels (119 µs baseline).
// ===========================================================================
__global__ __launch_bounds__(256) void wtrans_kernel(
    const float* __restrict__ Wq, const float* __restrict__ Wk,
    const float* __restrict__ Wv, unsigned short* __restrict__ wt)
{
    const int sel = blockIdx.x;
    const int c0  = blockIdx.y * 64;
    const float* W = (sel == 0) ? Wq : ((sel == 1) ? Wk : Wv);
    __shared__ unsigned short tile[64][72];
    const int tid = threadIdx.x;
    {
        const int c  = tid >> 2;
        const int hg = (tid & 3) * 16;
        const float* src = W + (size_t)(c0 + c) * 64 + hg;
        #pragma unroll
        for (int i = 0; i < 16; i++) tile[c][hg + i] = f2bf(src[i]);
    }
    __syncthreads();
    {
        const int h  = tid >> 2;
        const int cg = (tid & 3) * 16;
        unsigned short* dst = wt + ((size_t)sel * 64 + h) * 1024 + c0 + cg;
        #pragma unroll
        for (int i = 0; i < 16; i++) dst[i] = tile[cg + i][h];
    }
}

__global__ __launch_bounds__(512) void proj_fused_kernel(
    const float* __restrict__ x, const unsigned short* __restrict__ wt,
    unsigned short* __restrict__ ws)
{
    const int m0   = blockIdx.x * 32;
    const int tid  = threadIdx.x;
    const int wave = tid >> 6, lane = tid & 63;
    const int quad = lane >> 4, l16 = lane & 15;

    const unsigned short* wq = wt;
    const unsigned short* wk = wt + 65536;
    const unsigned short* wv = wt + 131072;

    __shared__ float lds[16896];

    f32x4 aq[2][4] = {}, ak[2][4] = {}, av[4][2] = {};

    const int kbase = wave * 128;
    const float* xrow0 = x + (size_t)(m0 + l16) * 1024 + kbase + quad * 8;
    const float* xrow1 = xrow0 + (size_t)16 * 1024;
    float4 xa0 = *(const float4*)(xrow0);
    float4 xb0 = *(const float4*)(xrow0 + 4);
    float4 xa1 = *(const float4*)(xrow1);
    float4 xb1 = *(const float4*)(xrow1 + 4);
    for (int kk = 0; kk < 128; kk += 32) {
        const int nk = (kk + 32) & 127;
        float4 na0 = *(const float4*)(xrow0 + nk);
        float4 nb0 = *(const float4*)(xrow0 + nk + 4);
        float4 na1 = *(const float4*)(xrow1 + nk);
        float4 nb1 = *(const float4*)(xrow1 + nk + 4);
        short8 af0 = pack8(xa0, xb0);
        short8 af1 = pack8(xa1, xb1);
        const int wo = kbase + kk + quad * 8;
        #pragma unroll
        for (int nt = 0; nt < 4; nt++) {
            const size_t ro = (size_t)(nt * 16 + l16) * 1024 + wo;
            short8 bq = *(const short8*)(wq + ro);
            short8 bk = *(const short8*)(wk + ro);
            short8 bv = *(const short8*)(wv + ro);
            aq[0][nt] = __builtin_amdgcn_mfma_f32_16x16x32_bf16(af0, bq, aq[0][nt], 0, 0, 0);
            aq[1][nt] = __builtin_amdgcn_mfma_f32_16x16x32_bf16(af1, bq, aq[1][nt], 0, 0, 0);
            ak[0][nt] = __builtin_amdgcn_mfma_f32_16x16x32_bf16(af0, bk, ak[0][nt], 0, 0, 0);
            ak[1][nt] = __builtin_amdgcn_mfma_f32_16x16x32_bf16(af1, bk, ak[1][nt], 0, 0, 0);
            av[nt][0] = __builtin_amdgcn_mfma_f32_16x16x32_bf16(bv, af0, av[nt][0], 0, 0, 0);
            av[nt][1] = __builtin_amdgcn_mfma_f32_16x16x32_bf16(bv, af1, av[nt][1], 0, 0, 0);
        }
        xa0 = na0; xb0 = nb0; xa1 = na1; xb1 = nb1;
    }

    const int b   = m0 >> 11;
    const int tb0 = m0 & 2047;
    const int rrow = tid >> 4, rh0 = (tid & 15) * 4;

    #pragma unroll
    for (int tf = 0; tf < 2; tf++)
        #pragma unroll
        for (int nt = 0; nt < 4; nt++)
            #pragma unroll
            for (int r = 0; r < 4; r++)
                lds[(wave * 32 + tf * 16 + quad * 4 + r) * 66 + nt * 16 + l16]
                    = aq[tf][nt][r];
    __syncthreads();
    {
        float s[4] = {0.f, 0.f, 0.f, 0.f};
        #pragma unroll
        for (int w = 0; w < 8; w++)
            #pragma unroll
            for (int i = 0; i < 4; i++)
                s[i] += lds[(w * 32 + rrow) * 66 + rh0 + i];
        #pragma unroll
        for (int i = 0; i < 4; i++)
            ws[(size_t)(m0 + rrow) * 64 + rh0 + i] = f2bf(s[i]);
    }
    __syncthreads();

    #pragma unroll
    for (int tf = 0; tf < 2; tf++)
        #pragma unroll
        for (int nt = 0; nt < 4; nt++)
            #pragma unroll
            for (int r = 0; r < 4; r++)
                lds[(wave * 32 + tf * 16 + quad * 4 + r) * 66 + nt * 16 + l16]
                    = ak[tf][nt][r];
    __syncthreads();
    {
        float s[4] = {0.f, 0.f, 0.f, 0.f};
        #pragma unroll
        for (int w = 0; w < 8; w++)
            #pragma unroll
            for (int i = 0; i < 4; i++)
                s[i] += lds[(w * 32 + rrow) * 66 + rh0 + i];
        #pragma unroll
        for (int i = 0; i < 4; i++)
            ws[NTOT + (size_t)(m0 + rrow) * 64 + rh0 + i] = f2bf(s[i]);
    }
    __syncthreads();

    #pragma unroll
    for (int nt = 0; nt < 4; nt++)
        #pragma unroll
        for (int tf = 0; tf < 2; tf++)
            #pragma unroll
            for (int r = 0; r < 4; r++)
                lds[(wave * 64 + nt * 16 + quad * 4 + r) * 33 + tf * 16 + l16]
                    = av[nt][tf][r];
    __syncthreads();
    {
        const int h = tid >> 3, t0 = (tid & 7) * 4;
        unsigned short* vdst = ws + 2 * NTOT + (size_t)b * 131072
                             + (size_t)h * 2048 + tb0;
        float s[4] = {0.f, 0.f, 0.f, 0.f};
        #pragma unroll
        for (int w = 0; w < 8; w++)
            #pragma unroll
            for (int i = 0; i < 4; i++)
                s[i] += lds[(w * 64 + h) * 33 + t0 + i];
        #pragma unroll
        for (int i = 0; i < 4; i++)
            vdst[t0 + i] = f2bf(s[i]);
    }
}

__global__ __launch_bounds__(512) void attn_fused_kernel(
    const unsigned short* __restrict__ ws, float* __restrict__ out)
{
    const int B    = blockIdx.x;
    const int xcd  = B & 7;
    const int slot = B >> 3;
    const int b    = xcd & 3;
    const int qt   = (slot << 1) | (xcd >> 2);
    const int q0 = qt * 16;
    const int tid  = threadIdx.x;
    const int wave = tid >> 6, lane = tid & 63;
    const int quad = lane >> 4, l16 = lane & 15;

    const unsigned short* Q  = ws + (size_t)b * 131072;
    const unsigned short* K  = ws + NTOT + (size_t)b * 131072;
    const unsigned short* VT = ws + 2 * NTOT + (size_t)b * 131072;

    __shared__ unsigned short p_lds[8][16][72];
    __shared__ float o_red[8][16][68];
    __shared__ float ml_red[8][2][16];

    const int qrow = q0 + l16;
    short8 qf0 = *(const short8*)(Q + (size_t)qrow * 64 + quad * 8);
    short8 qf1 = *(const short8*)(Q + (size_t)qrow * 64 + 32 + quad * 8);

    f32x4 o[4] = {};
    float m_i[4], l_i[4];
    #pragma unroll
    for (int r = 0; r < 4; r++) { m_i[r] = -1e30f; l_i[r] = 0.f; }

    const int qi = q0 + quad * 4;
    const int nkt = (qt >> 2) + 1;

    for (int t = wave; t < nkt; t += 8) {
        const int j0 = t * 64;
        f32x4 s[4] = {};
        #pragma unroll
        for (int nt = 0; nt < 4; nt++) {
            const unsigned short* kp = K + (size_t)(j0 + nt * 16 + l16) * 64 + quad * 8;
            short8 kf0 = *(const short8*)(kp);
            short8 kf1 = *(const short8*)(kp + 32);
            s[nt] = __builtin_amdgcn_mfma_f32_16x16x32_bf16(qf0, kf0, s[nt], 0, 0, 0);
            s[nt] = __builtin_amdgcn_mfma_f32_16x16x32_bf16(qf1, kf1, s[nt], 0, 0, 0);
        }
        float pm[4] = {-1e30f, -1e30f, -1e30f, -1e30f};
        #pragma unroll
        for (int nt = 0; nt < 4; nt++) {
            const int kj = j0 + nt * 16 + l16;
            #pragma unroll
            for (int r = 0; r < 4; r++) {
                float v = s[nt][r] * 0.125f;
                v = (kj > qi + r || v == 0.0f) ? -1e30f : v;
                s[nt][r] = v;
                pm[r] = fmaxf(pm[r], v);
            }
        }
        #pragma unroll
        for (int off = 1; off < 16; off <<= 1)
            #pragma unroll
            for (int r = 0; r < 4; r++)
                pm[r] = fmaxf(pm[r], __shfl_xor(pm[r], off));
        float alpha[4];
        #pragma unroll
        for (int r = 0; r < 4; r++) {
            float mn = fmaxf(m_i[r], pm[r]);
            alpha[r] = __expf(m_i[r] - mn);
            m_i[r] = mn;
        }
        float ps[4] = {0.f, 0.f, 0.f, 0.f};
        #pragma unroll
        for (int nt = 0; nt < 4; nt++)
            #pragma unroll
            for (int r = 0; r < 4; r++) {
                float p = __expf(s[nt][r] - m_i[r]);
                ps[r] += p;
                p_lds[wave][quad * 4 + r][nt * 16 + l16] = f2bf(p);
            }
        #pragma unroll
        for (int off = 1; off < 16; off <<= 1)
            #pragma unroll
            for (int r = 0; r < 4; r++)
                ps[r] += __shfl_xor(ps[r], off);
        #pragma unroll
        for (int r = 0; r < 4; r++) l_i[r] = l_i[r] * alpha[r] + ps[r];
        #pragma unroll
        for (int ht = 0; ht < 4; ht++)
            #pragma unroll
            for (int r = 0; r < 4; r++)
                o[ht][r] *= alpha[r];
        #pragma unroll
        for (int ks = 0; ks < 2; ks++) {
            short8 pf = *(const short8*)&p_lds[wave][l16][ks * 32 + quad * 8];
            #pragma unroll
            for (int ht = 0; ht < 4; ht++) {
                short8 vf = *(const short8*)(VT + (size_t)(ht * 16 + l16) * 2048 + j0 + ks * 32 + quad * 8);
                o[ht] = __builtin_amdgcn_mfma_f32_16x16x32_bf16(pf, vf, o[ht], 0, 0, 0);
            }
        }
    }

    #pragma unroll
    for (int ht = 0; ht < 4; ht++)
        #pragma unroll
        for (int r = 0; r < 4; r++)
            o_red[wave][quad * 4 + r][ht * 16 + l16] = o[ht][r];
    if (l16 == 0) {
        #pragma unroll
        for (int r = 0; r < 4; r++) {
            ml_red[wave][0][quad * 4 + r] = m_i[r];
            ml_red[wave][1][quad * 4 + r] = l_i[r];
        }
    }
    __syncthreads();

    const int row = tid >> 5, c0 = (tid & 31) * 2;
    float M = -1e30f;
    #pragma unroll
    for (int w = 0; w < 8; w++) M = fmaxf(M, ml_red[w][0][row]);
    float wgt[8];
    float l = 0.f;
    #pragma unroll
    for (int w = 0; w < 8; w++) {
        wgt[w] = __expf(ml_red[w][0][row] - M);
        l += wgt[w] * ml_red[w][1][row];
    }
    const float inv = 1.0f / l;
    float* op = out + ((size_t)b * 2048 + q0 + row) * 64 + c0;
    #pragma unroll
    for (int i = 0; i < 2; i++) {
        float sv = 0.f;
        #pragma unroll
        for (int w = 0; w < 8; w++) sv += wgt[w] * o_red[w][row][c0 + i];
        op[i] = sv * inv;
    }
}

// ===========================================================================
// Cooperative fused kernel: 256 blocks x 512 threads (1 block/CU guaranteed
// co-resident: LDS 67.6KB, 8 waves, VGPR<=256 via __launch_bounds__(512,2)).
// wtrans -> [rel-fence, grid.sync, acq-fence] -> proj (proven 32-row body)
//        -> [rel-fence, grid.sync, acq-fence] -> attn (proven body x2 jobs).
// The acquire-side __threadfence() AFTER grid.sync is essential: per-XCD L2s
// are non-coherent; without buffer_inv the consumer reads stale (poison/zero)
// lines -- that was round-1's failure (absmax 3.97 = zeros / 468 = poison).
// ===========================================================================
__global__ __launch_bounds__(512, 2) void fused_all(
    const float* __restrict__ x, const float* __restrict__ Wq,
    const float* __restrict__ Wk, const float* __restrict__ Wv,
    unsigned short* __restrict__ ws, float* __restrict__ out)
{
    cg::grid_group grid = cg::this_grid();
    __shared__ __align__(16) char smem[67584];   // max(proj 67584, attn 54272)
    const int blk  = blockIdx.x;
    const int tid  = threadIdx.x;
    const int wave = tid >> 6, lane = tid & 63;
    const int quad = lane >> 4, l16 = lane & 15;
    unsigned short* wt = ws + WT_OFF;

    // ---- phase 0: W transpose (blocks 0..47) ----
    if (blk < 48) {
        const int sel = blk >> 4;
        const int c0  = (blk & 15) * 64;
        const float* W = (sel == 0) ? Wq : ((sel == 1) ? Wk : Wv);
        unsigned short (*tile)[72] = (unsigned short (*)[72])smem;
        if (tid < 256) {
            const int c  = tid >> 2;
            const int hg = (tid & 3) * 16;
            const float* src = W + (size_t)(c0 + c) * 64 + hg;
            #pragma unroll
            for (int i = 0; i < 16; i++) tile[c][hg + i] = f2bf(src[i]);
        }
        __syncthreads();
        if (tid < 256) {
            const int h   = tid >> 2;
            const int cg0 = (tid & 3) * 16;
            unsigned short* dst = wt + ((size_t)sel * 64 + h) * 1024 + c0 + cg0;
            #pragma unroll
            for (int i = 0; i < 16; i++) dst[i] = tile[cg0 + i][h];
        }
    }
    __threadfence();   // release: flush wT out of producer L2
    grid.sync();
    __threadfence();   // acquire: invalidate consumer L1/L2 before reading wT

    // ---- phase B: fused projections (proven body; m0 = blk*32) ----
    {
        const int m0 = blk * 32;
        const unsigned short* wq = wt;
        const unsigned short* wk = wt + 65536;
        const unsigned short* wv = wt + 131072;
        float* lds = (float*)smem;

        f32x4 aq[2][4] = {}, ak[2][4] = {}, av[4][2] = {};

        const int kbase = wave * 128;
        const float* xrow0 = x + (size_t)(m0 + l16) * 1024 + kbase + quad * 8;
        const float* xrow1 = xrow0 + (size_t)16 * 1024;
        float4 xa0 = *(const float4*)(xrow0);
        float4 xb0 = *(const float4*)(xrow0 + 4);
        float4 xa1 = *(const float4*)(xrow1);
        float4 xb1 = *(const float4*)(xrow1 + 4);
        for (int kk = 0; kk < 128; kk += 32) {
            const int nk = (kk + 32) & 127;
            float4 na0 = *(const float4*)(xrow0 + nk);
            float4 nb0 = *(const float4*)(xrow0 + nk + 4);
            float4 na1 = *(const float4*)(xrow1 + nk);
            float4 nb1 = *(const float4*)(xrow1 + nk + 4);
            short8 af0 = pack8(xa0, xb0);
            short8 af1 = pack8(xa1, xb1);
            const int wo = kbase + kk + quad * 8;
            #pragma unroll
            for (int nt = 0; nt < 4; nt++) {
                const size_t ro = (size_t)(nt * 16 + l16) * 1024 + wo;
                short8 bq = *(const short8*)(wq + ro);
                short8 bk = *(const short8*)(wk + ro);
                short8 bv = *(const short8*)(wv + ro);
                aq[0][nt] = __builtin_amdgcn_mfma_f32_16x16x32_bf16(af0, bq, aq[0][nt], 0, 0, 0);
                aq[1][nt] = __builtin_amdgcn_mfma_f32_16x16x32_bf16(af1, bq, aq[1][nt], 0, 0, 0);
                ak[0][nt] = __builtin_amdgcn_mfma_f32_16x16x32_bf16(af0, bk, ak[0][nt], 0, 0, 0);
                ak[1][nt] = __builtin_amdgcn_mfma_f32_16x16x32_bf16(af1, bk, ak[1][nt], 0, 0, 0);
                av[nt][0] = __builtin_amdgcn_mfma_f32_16x16x32_bf16(bv, af0, av[nt][0], 0, 0, 0);
                av[nt][1] = __builtin_amdgcn_mfma_f32_16x16x32_bf16(bv, af1, av[nt][1], 0, 0, 0);
            }
            xa0 = na0; xb0 = nb0; xa1 = na1; xb1 = nb1;
        }

        const int b   = m0 >> 11;
        const int tb0 = m0 & 2047;
        const int rrow = tid >> 4, rh0 = (tid & 15) * 4;

        // phase Q
        #pragma unroll
        for (int tf = 0; tf < 2; tf++)
            #pragma unroll
            for (int nt = 0; nt < 4; nt++)
                #pragma unroll
                for (int r = 0; r < 4; r++)
                    lds[(wave * 32 + tf * 16 + quad * 4 + r) * 66 + nt * 16 + l16]
                        = aq[tf][nt][r];
        __syncthreads();
        {
            float s[4] = {0.f, 0.f, 0.f, 0.f};
            #pragma unroll
            for (int w = 0; w < 8; w++)
                #pragma unroll
                for (int i = 0; i < 4; i++)
                    s[i] += lds[(w * 32 + rrow) * 66 + rh0 + i];
            #pragma unroll
            for (int i = 0; i < 4; i++)
                ws[(size_t)(m0 + rrow) * 64 + rh0 + i] = f2bf(s[i]);
        }
        __syncthreads();

        // phase K
        #pragma unroll
        for (int tf = 0; tf < 2; tf++)
            #pragma unroll
            for (int nt = 0; nt < 4; nt++)
                #pragma unroll
                for (int r = 0; r < 4; r++)
                    lds[(wave * 32 + tf * 16 + quad * 4 + r) * 66 + nt * 16 + l16]
                        = ak[tf][nt][r];
        __syncthreads();
        {
            float s[4] = {0.f, 0.f, 0.f, 0.f};
            #pragma unroll
            for (int w = 0; w < 8; w++)
                #pragma unroll
                for (int i = 0; i < 4; i++)
                    s[i] += lds[(w * 32 + rrow) * 66 + rh0 + i];
            #pragma unroll
            for (int i = 0; i < 4; i++)
                ws[NTOT + (size_t)(m0 + rrow) * 64 + rh0 + i] = f2bf(s[i]);
        }
        __syncthreads();

        // phase V
        #pragma unroll
        for (int nt = 0; nt < 4; nt++)
            #pragma unroll
            for (int tf = 0; tf < 2; tf++)
                #pragma unroll
                for (int r = 0; r < 4; r++)
                    lds[(wave * 64 + nt * 16 + quad * 4 + r) * 33 + tf * 16 + l16]
                        = av[nt][tf][r];
        __syncthreads();
        {
            const int h = tid >> 3, t0 = (tid & 7) * 4;
            unsigned short* vdst = ws + 2 * NTOT + (size_t)b * 131072
                                 + (size_t)h * 2048 + tb0;
            float s[4] = {0.f, 0.f, 0.f, 0.f};
            #pragma unroll
            for (int w = 0; w < 8; w++)
                #pragma unroll
                for (int i = 0; i < 4; i++)
                    s[i] += lds[(w * 64 + h) * 33 + t0 + i];
            #pragma unroll
            for (int i = 0; i < 4; i++)
                vdst[t0 + i] = f2bf(s[i]);
        }
    }
    __threadfence();   // release: flush q/k/vT
    grid.sync();
    __threadfence();   // acquire: invalidate before reading q/k/vT

    // ---- phase C: flash attention, 2 jobs per block (proven body) ----
    unsigned short (*p_lds)[16][72] = (unsigned short (*)[16][72])smem;
    float (*o_red)[16][68] = (float (*)[16][68])(smem + 18432);
    float (*ml_red)[2][16] = (float (*)[2][16])(smem + 53248);

    for (int sub = 0; sub < 2; sub++) {
        const int Bj   = blk + 256 * sub;
        const int xcd  = Bj & 7;
        const int slot = Bj >> 3;
        const int b    = xcd & 3;
        const int qt   = (slot << 1) | (xcd >> 2);   // 0..127
        const int q0   = qt * 16;

        const unsigned short* Q  = ws + (size_t)b * 131072;
        const unsigned short* K  = ws + NTOT + (size_t)b * 131072;
        const unsigned short* VT = ws + 2 * NTOT + (size_t)b * 131072;

        const int qrow = q0 + l16;
        short8 qf0 = *(const short8*)(Q + (size_t)qrow * 64 + quad * 8);
        short8 qf1 = *(const short8*)(Q + (size_t)qrow * 64 + 32 + quad * 8);

        f32x4 o[4] = {};
        float m_i[4], l_i[4];
        #pragma unroll
        for (int r = 0; r < 4; r++) { m_i[r] = -1e30f; l_i[r] = 0.f; }

        const int qi = q0 + quad * 4;
        const int nkt = (qt >> 2) + 1;

        for (int t = wave; t < nkt; t += 8) {
            const int j0 = t * 64;
            f32x4 s[4] = {};
            #pragma unroll
            for (int nt = 0; nt < 4; nt++) {
                const unsigned short* kp = K + (size_t)(j0 + nt * 16 + l16) * 64 + quad * 8;
                short8 kf0 = *(const short8*)(kp);
                short8 kf1 = *(const short8*)(kp + 32);
                s[nt] = __builtin_amdgcn_mfma_f32_16x16x32_bf16(qf0, kf0, s[nt], 0, 0, 0);
                s[nt] = __builtin_amdgcn_mfma_f32_16x16x32_bf16(qf1, kf1, s[nt], 0, 0, 0);
            }
            float pm[4] = {-1e30f, -1e30f, -1e30f, -1e30f};
            #pragma unroll
            for (int nt = 0; nt < 4; nt++) {
                const int kj = j0 + nt * 16 + l16;
                #pragma unroll
                for (int r = 0; r < 4; r++) {
                    float v = s[nt][r] * 0.125f;
                    v = (kj > qi + r || v == 0.0f) ? -1e30f : v;  // causal + ==0 quirk
                    s[nt][r] = v;
                    pm[r] = fmaxf(pm[r], v);
                }
            }
            #pragma unroll
            for (int off = 1; off < 16; off <<= 1)
                #pragma unroll
                for (int r = 0; r < 4; r++)
                    pm[r] = fmaxf(pm[r], __shfl_xor(pm[r], off));
            float alpha[4];
            #pragma unroll
            for (int r = 0; r < 4; r++) {
                float mn = fmaxf(m_i[r], pm[r]);
                alpha[r] = __expf(m_i[r] - mn);
                m_i[r] = mn;
            }
            float ps[4] = {0.f, 0.f, 0.f, 0.f};
            #pragma unroll
            for (int nt = 0; nt < 4; nt++)
                #pragma unroll
                for (int r = 0; r < 4; r++) {
                    float p = __expf(s[nt][r] - m_i[r]);
                    ps[r] += p;
                    p_lds[wave][quad * 4 + r][nt * 16 + l16] = f2bf(p);
                }
            #pragma unroll
            for (int off = 1; off < 16; off <<= 1)
                #pragma unroll
                for (int r = 0; r < 4; r++)
                    ps[r] += __shfl_xor(ps[r], off);
            #pragma unroll
            for (int r = 0; r < 4; r++) l_i[r] = l_i[r] * alpha[r] + ps[r];
            #pragma unroll
            for (int ht = 0; ht < 4; ht++)
                #pragma unroll
                for (int r = 0; r < 4; r++)
                    o[ht][r] *= alpha[r];
            #pragma unroll
            for (int ks = 0; ks < 2; ks++) {
                short8 pf = *(const short8*)&p_lds[wave][l16][ks * 32 + quad * 8];
                #pragma unroll
                for (int ht = 0; ht < 4; ht++) {
                    short8 vf = *(const short8*)(VT + (size_t)(ht * 16 + l16) * 2048 + j0 + ks * 32 + quad * 8);
                    o[ht] = __builtin_amdgcn_mfma_f32_16x16x32_bf16(pf, vf, o[ht], 0, 0, 0);
                }
            }
        }

        #pragma unroll
        for (int ht = 0; ht < 4; ht++)
            #pragma unroll
            for (int r = 0; r < 4; r++)
                o_red[wave][quad * 4 + r][ht * 16 + l16] = o[ht][r];
        if (l16 == 0) {
            #pragma unroll
            for (int r = 0; r < 4; r++) {
                ml_red[wave][0][quad * 4 + r] = m_i[r];
                ml_red[wave][1][quad * 4 + r] = l_i[r];
            }
        }
        __syncthreads();

        const int row = tid >> 5, c0 = (tid & 31) * 2;
        float M = -1e30f;
        #pragma unroll
        for (int w = 0; w < 8; w++) M = fmaxf(M, ml_red[w][0][row]);
        float wgt[8];
        float l = 0.f;
        #pragma unroll
        for (int w = 0; w < 8; w++) {
            wgt[w] = __expf(ml_red[w][0][row] - M);
            l += wgt[w] * ml_red[w][1][row];
        }
        const float inv = 1.0f / l;
        float* op = out + ((size_t)b * 2048 + q0 + row) * 64 + c0;
        #pragma unroll
        for (int i = 0; i < 2; i++) {
            float sv = 0.f;
            #pragma unroll
            for (int w = 0; w < 8; w++) sv += wgt[w] * o_red[w][row][c0 + i];
            op[i] = sv * inv;
        }
        __syncthreads();   // o_red/ml_red reuse hazard between sub jobs
    }
}

// ---------------------------------------------------------------------------
extern "C" void kernel_launch(void* const* d_in, const int* in_sizes, int n_in,
                              void* d_out, int out_size, void* d_ws, size_t ws_size,
                              hipStream_t stream) {
    const float* x  = (const float*)d_in[0];
    const float* Wq = (const float*)d_in[1];
    const float* Wk = (const float*)d_in[2];
    const float* Wv = (const float*)d_in[3];
    float* out = (float*)d_out;
    unsigned short* ws = (unsigned short*)d_ws;

    void* args[6] = { (void*)&x, (void*)&Wq, (void*)&Wk, (void*)&Wv,
                      (void*)&ws, (void*)&out };
    hipError_t e = hipLaunchCooperativeKernel(
        reinterpret_cast<const void*>(&fused_all),
        dim3(256), dim3(512), args, 0, stream);
    if (e != hipSuccess) {
        // cooperative launch rejected -> proven 3-kernel fallback
        (void)hipGetLastError();
        unsigned short* wT = ws + WT_OFF;
        wtrans_kernel<<<dim3(3, 16), 256, 0, stream>>>(Wq, Wk, Wv, wT);
        proj_fused_kernel<<<dim3(256), 512, 0, stream>>>(x, wT, ws);
        attn_fused_kernel<<<dim3(512), 512, 0, stream>>>(ws, out);
    }
}

// Round 4
// 129.317 us; speedup vs baseline: 2.6628x; 2.6628x over previous
//
#include <hip/hip_runtime.h>

// B=4, T=2048, C=1024, H=64. fp32 in/out, bf16 MFMA internally.
// ws layout (u16 elements):
//   [0,        524288)  q  bf16  [b*2048+t][64]
//   [524288,  1048576)  k  bf16  [b*2048+t][64]
//   [1048576, 1572864)  vT bf16  [b][h][t]   (b*131072 + h*2048 + t)
//   [1572864, 1769472)  wT bf16  [sel][h][c] (sel*65536 + h*1024 + c)
//
// Round-4 = round-3 resubmission (round-3 bench died on GPU acquisition
// timeout; kernel never ran). Structure: proven 3-kernel pipeline
// (119 us baseline), with
//  - proj split 32->16 rows/block (512 blocks): accum VGPRs 96->48 so
//    __launch_bounds__(512,4) fits 2 blocks/CU -> 16 waves/CU (2x occupancy,
//    identical arithmetic / summation order as baseline).
//  - attn: s_setprio(1) around MFMA clusters (T5; +4-7% measured on attn).
// Cooperative fusion abandoned: round-2 showed grid.sync+fence machinery
// costs ~260 us of pure stall (MfmaUtil 0.8%, VALUBusy 2.5% over 270 us).

typedef __attribute__((ext_vector_type(8))) short short8;
typedef __attribute__((ext_vector_type(4))) float f32x4;

#define NTOT 524288   // 8192*64
#define WT_OFF (3 * NTOT)

__device__ __forceinline__ unsigned short f2bf(float f) {
    unsigned int u = __builtin_bit_cast(unsigned int, f);
    return (unsigned short)((u + 0x7fffu + ((u >> 16) & 1u)) >> 16);
}

__device__ __forceinline__ unsigned int pack2(float a, float b) {
    return (unsigned int)f2bf(a) | ((unsigned int)f2bf(b) << 16);
}

__device__ __forceinline__ short8 pack8(float4 a, float4 b) {
    short8 r;
    r[0] = (short)f2bf(a.x); r[1] = (short)f2bf(a.y);
    r[2] = (short)f2bf(a.z); r[3] = (short)f2bf(a.w);
    r[4] = (short)f2bf(b.x); r[5] = (short)f2bf(b.y);
    r[6] = (short)f2bf(b.z); r[7] = (short)f2bf(b.w);
    return r;
}

// ---------------------------------------------------------------------------
// Kernel 1: transpose W (fp32 [1024][64]) -> wT bf16 [64][1024], x3 matrices
// (unchanged, proven)
// ---------------------------------------------------------------------------
__global__ __launch_bounds__(256) void wtrans_kernel(
    const float* __restrict__ Wq, const float* __restrict__ Wk,
    const float* __restrict__ Wv, unsigned short* __restrict__ wt)
{
    const int sel = blockIdx.x;
    const int c0  = blockIdx.y * 64;
    const float* W = (sel == 0) ? Wq : ((sel == 1) ? Wk : Wv);
    __shared__ unsigned short tile[64][72];
    const int tid = threadIdx.x;
    {
        const int c  = tid >> 2;
        const int hg = (tid & 3) * 16;
        const float* src = W + (size_t)(c0 + c) * 64 + hg;
        #pragma unroll
        for (int i = 0; i < 16; i++) tile[c][hg + i] = f2bf(src[i]);
    }
    __syncthreads();
    {
        const int h  = tid >> 2;
        const int cg = (tid & 3) * 16;
        unsigned short* dst = wt + ((size_t)sel * 64 + h) * 1024 + c0 + cg;
        #pragma unroll
        for (int i = 0; i < 16; i++) dst[i] = tile[cg + i][h];
    }
}

// ---------------------------------------------------------------------------
// Kernel 2: fused projections. 512 blocks x 512 threads (8 waves), 16 t-rows
// per block. Wave w covers K in [w*128,(w+1)*128) -> 4 iters of (12 MFMA +
// 12 loads). Accumulators 48 VGPR -> fits 128-VGPR cap -> 2 blocks/CU
// (16 waves/CU), double the latency hiding of the 32-row baseline.
// Identical per-element summation order as baseline (each wave's k-split and
// nt mapping unchanged) -> bitwise-identical q/k/vT.
// ---------------------------------------------------------------------------
__global__ __launch_bounds__(512, 4) void proj_fused_kernel(
    const float* __restrict__ x, const unsigned short* __restrict__ wt,
    unsigned short* __restrict__ ws)
{
    const int m0   = blockIdx.x * 16;
    const int tid  = threadIdx.x;
    const int wave = tid >> 6, lane = tid & 63;   // wave 0..7
    const int quad = lane >> 4, l16 = lane & 15;

    const unsigned short* wq = wt;
    const unsigned short* wk = wt + 65536;
    const unsigned short* wv = wt + 131072;

    // shared scratch, reused per phase:
    //   q/k phases: [8][16][66] floats (idx (w*16+t)*66 + h)   = 8448
    //   v phase:    [8][64][17] floats (idx (w*64+h)*17 + t)   = 8704
    __shared__ float lds[8704];   // 34.8 KB

    f32x4 aq[4] = {}, ak[4] = {}, av[4] = {};

    const int kbase = wave * 128;
    const float* xrow = x + (size_t)(m0 + l16) * 1024 + kbase + quad * 8;
    float4 xa = *(const float4*)(xrow);
    float4 xb = *(const float4*)(xrow + 4);
    for (int kk = 0; kk < 128; kk += 32) {
        const int nk = (kk + 32) & 127;     // wraps on last iter (unused)
        float4 na = *(const float4*)(xrow + nk);
        float4 nb = *(const float4*)(xrow + nk + 4);
        short8 af = pack8(xa, xb);
        const int wo = kbase + kk + quad * 8;
        #pragma unroll
        for (int nt = 0; nt < 4; nt++) {
            const size_t ro = (size_t)(nt * 16 + l16) * 1024 + wo;
            short8 bq = *(const short8*)(wq + ro);
            short8 bk = *(const short8*)(wk + ro);
            short8 bv = *(const short8*)(wv + ro);
            aq[nt] = __builtin_amdgcn_mfma_f32_16x16x32_bf16(af, bq, aq[nt], 0, 0, 0);
            ak[nt] = __builtin_amdgcn_mfma_f32_16x16x32_bf16(af, bk, ak[nt], 0, 0, 0);
            av[nt] = __builtin_amdgcn_mfma_f32_16x16x32_bf16(bv, af, av[nt], 0, 0, 0);
        }
        xa = na; xb = nb;
    }

    const int b   = m0 >> 11;
    const int tb0 = m0 & 2047;
    const int rrow = tid >> 5, rh0 = (tid & 31) * 2;   // q/k reduce mapping

    // ---- phase Q: stash [8][16][66], 8-way reduce, store 2 bf16/thread ----
    #pragma unroll
    for (int nt = 0; nt < 4; nt++)
        #pragma unroll
        for (int r = 0; r < 4; r++)
            lds[(wave * 16 + quad * 4 + r) * 66 + nt * 16 + l16] = aq[nt][r];
    __syncthreads();
    {
        float s0 = 0.f, s1 = 0.f;
        #pragma unroll
        for (int w = 0; w < 8; w++) {
            s0 += lds[(w * 16 + rrow) * 66 + rh0];
            s1 += lds[(w * 16 + rrow) * 66 + rh0 + 1];
        }
        *(unsigned int*)(ws + (size_t)(m0 + rrow) * 64 + rh0) = pack2(s0, s1);
    }
    __syncthreads();

    // ---- phase K ----
    #pragma unroll
    for (int nt = 0; nt < 4; nt++)
        #pragma unroll
        for (int r = 0; r < 4; r++)
            lds[(wave * 16 + quad * 4 + r) * 66 + nt * 16 + l16] = ak[nt][r];
    __syncthreads();
    {
        float s0 = 0.f, s1 = 0.f;
        #pragma unroll
        for (int w = 0; w < 8; w++) {
            s0 += lds[(w * 16 + rrow) * 66 + rh0];
            s1 += lds[(w * 16 + rrow) * 66 + rh0 + 1];
        }
        *(unsigned int*)(ws + NTOT + (size_t)(m0 + rrow) * 64 + rh0) = pack2(s0, s1);
    }
    __syncthreads();

    // ---- phase V: av[nt][r] -> h = nt*16+quad*4+r, t = l16 ----
    #pragma unroll
    for (int nt = 0; nt < 4; nt++)
        #pragma unroll
        for (int r = 0; r < 4; r++)
            lds[(wave * 64 + nt * 16 + quad * 4 + r) * 17 + l16] = av[nt][r];
    __syncthreads();
    {
        const int h = tid >> 3, t0 = (tid & 7) * 2;
        float s0 = 0.f, s1 = 0.f;
        #pragma unroll
        for (int w = 0; w < 8; w++) {
            s0 += lds[(w * 64 + h) * 17 + t0];
            s1 += lds[(w * 64 + h) * 17 + t0 + 1];
        }
        *(unsigned int*)(ws + 2 * NTOT + (size_t)b * 131072
                         + (size_t)h * 2048 + tb0 + t0) = pack2(s0, s1);
    }
}

// ---------------------------------------------------------------------------
// Kernel 3: fused flash attention, 8-way in-block K-split + XCD swizzle.
// Baseline-proven body + s_setprio around the MFMA clusters (T5).
// ---------------------------------------------------------------------------
__global__ __launch_bounds__(512) void attn_fused_kernel(
    const unsigned short* __restrict__ ws, float* __restrict__ out)
{
    const int B    = blockIdx.x;
    const int xcd  = B & 7;
    const int slot = B >> 3;
    const int b    = xcd & 3;
    const int qt   = (slot << 1) | (xcd >> 2);   // 0..127
    const int q0 = qt * 16;
    const int tid  = threadIdx.x;
    const int wave = tid >> 6, lane = tid & 63;  // wave 0..7
    const int quad = lane >> 4, l16 = lane & 15;

    const unsigned short* Q  = ws + (size_t)b * 131072;
    const unsigned short* K  = ws + NTOT + (size_t)b * 131072;
    const unsigned short* VT = ws + 2 * NTOT + (size_t)b * 131072;

    __shared__ unsigned short p_lds[8][16][72];  // per-wave P scratch
    __shared__ float o_red[8][16][68];           // per-wave partial O
    __shared__ float ml_red[8][2][16];           // per-wave m / l

    const int qrow = q0 + l16;
    short8 qf0 = *(const short8*)(Q + (size_t)qrow * 64 + quad * 8);
    short8 qf1 = *(const short8*)(Q + (size_t)qrow * 64 + 32 + quad * 8);

    f32x4 o[4] = {};
    float m_i[4], l_i[4];
    #pragma unroll
    for (int r = 0; r < 4; r++) { m_i[r] = -1e30f; l_i[r] = 0.f; }

    const int qi = q0 + quad * 4;
    const int nkt = (qt >> 2) + 1;

    for (int t = wave; t < nkt; t += 8) {
        const int j0 = t * 64;
        f32x4 s[4] = {};
        __builtin_amdgcn_s_setprio(1);
        #pragma unroll
        for (int nt = 0; nt < 4; nt++) {
            const unsigned short* kp = K + (size_t)(j0 + nt * 16 + l16) * 64 + quad * 8;
            short8 kf0 = *(const short8*)(kp);
            short8 kf1 = *(const short8*)(kp + 32);
            s[nt] = __builtin_amdgcn_mfma_f32_16x16x32_bf16(qf0, kf0, s[nt], 0, 0, 0);
            s[nt] = __builtin_amdgcn_mfma_f32_16x16x32_bf16(qf1, kf1, s[nt], 0, 0, 0);
        }
        __builtin_amdgcn_s_setprio(0);
        float pm[4] = {-1e30f, -1e30f, -1e30f, -1e30f};
        #pragma unroll
        for (int nt = 0; nt < 4; nt++) {
            const int kj = j0 + nt * 16 + l16;
            #pragma unroll
            for (int r = 0; r < 4; r++) {
                float v = s[nt][r] * 0.125f;
                v = (kj > qi + r || v == 0.0f) ? -1e30f : v;  // causal + ==0 quirk
                s[nt][r] = v;
                pm[r] = fmaxf(pm[r], v);
            }
        }
        #pragma unroll
        for (int off = 1; off < 16; off <<= 1)
            #pragma unroll
            for (int r = 0; r < 4; r++)
                pm[r] = fmaxf(pm[r], __shfl_xor(pm[r], off));
        float alpha[4];
        #pragma unroll
        for (int r = 0; r < 4; r++) {
            float mn = fmaxf(m_i[r], pm[r]);
            alpha[r] = __expf(m_i[r] - mn);
            m_i[r] = mn;
        }
        float ps[4] = {0.f, 0.f, 0.f, 0.f};
        #pragma unroll
        for (int nt = 0; nt < 4; nt++)
            #pragma unroll
            for (int r = 0; r < 4; r++) {
                float p = __expf(s[nt][r] - m_i[r]);
                ps[r] += p;
                p_lds[wave][quad * 4 + r][nt * 16 + l16] = f2bf(p);
            }
        #pragma unroll
        for (int off = 1; off < 16; off <<= 1)
            #pragma unroll
            for (int r = 0; r < 4; r++)
                ps[r] += __shfl_xor(ps[r], off);
        #pragma unroll
        for (int r = 0; r < 4; r++) l_i[r] = l_i[r] * alpha[r] + ps[r];
        #pragma unroll
        for (int ht = 0; ht < 4; ht++)
            #pragma unroll
            for (int r = 0; r < 4; r++)
                o[ht][r] *= alpha[r];
        __builtin_amdgcn_s_setprio(1);
        #pragma unroll
        for (int ks = 0; ks < 2; ks++) {
            short8 pf = *(const short8*)&p_lds[wave][l16][ks * 32 + quad * 8];
            #pragma unroll
            for (int ht = 0; ht < 4; ht++) {
                short8 vf = *(const short8*)(VT + (size_t)(ht * 16 + l16) * 2048 + j0 + ks * 32 + quad * 8);
                o[ht] = __builtin_amdgcn_mfma_f32_16x16x32_bf16(pf, vf, o[ht], 0, 0, 0);
            }
        }
        __builtin_amdgcn_s_setprio(0);
    }

    // ---- stash per-wave partial state ----
    #pragma unroll
    for (int ht = 0; ht < 4; ht++)
        #pragma unroll
        for (int r = 0; r < 4; r++)
            o_red[wave][quad * 4 + r][ht * 16 + l16] = o[ht][r];
    if (l16 == 0) {
        #pragma unroll
        for (int r = 0; r < 4; r++) {
            ml_red[wave][0][quad * 4 + r] = m_i[r];
            ml_red[wave][1][quad * 4 + r] = l_i[r];
        }
    }
    __syncthreads();

    // ---- 8-way combine: thread -> (row = tid>>5, col0 = (tid&31)*2) ----
    const int row = tid >> 5, c0 = (tid & 31) * 2;
    float M = -1e30f;
    #pragma unroll
    for (int w = 0; w < 8; w++) M = fmaxf(M, ml_red[w][0][row]);
    float wgt[8];
    float l = 0.f;
    #pragma unroll
    for (int w = 0; w < 8; w++) {
        wgt[w] = __expf(ml_red[w][0][row] - M);
        l += wgt[w] * ml_red[w][1][row];
    }
    const float inv = 1.0f / l;
    float* op = out + ((size_t)b * 2048 + q0 + row) * 64 + c0;
    #pragma unroll
    for (int i = 0; i < 2; i++) {
        const int col = c0 + i;
        float sv = 0.f;
        #pragma unroll
        for (int w = 0; w < 8; w++) sv += wgt[w] * o_red[w][row][col];
        op[i] = sv * inv;
    }
}

// ---------------------------------------------------------------------------
extern "C" void kernel_launch(void* const* d_in, const int* in_sizes, int n_in,
                              void* d_out, int out_size, void* d_ws, size_t ws_size,
                              hipStream_t stream) {
    const float* x  = (const float*)d_in[0];
    const float* Wq = (const float*)d_in[1];
    const float* Wk = (const float*)d_in[2];
    const float* Wv = (const float*)d_in[3];
    float* out = (float*)d_out;
    unsigned short* ws = (unsigned short*)d_ws;
    unsigned short* wT = ws + WT_OFF;

    wtrans_kernel<<<dim3(3, 16), 256, 0, stream>>>(Wq, Wk, Wv, wT);
    proj_fused_kernel<<<dim3(512), 512, 0, stream>>>(x, wT, ws);
    attn_fused_kernel<<<dim3(512), 512, 0, stream>>>(ws, out);
}

// Round 5
// 119.546 us; speedup vs baseline: 2.8805x; 1.0817x over previous
//
#include <hip/hip_runtime.h>

// B=4, T=2048, C=1024, H=64. fp32 in/out, bf16 MFMA internally.
// ws layout (u16 elements):
//   [0,        524288)  q  bf16  [b*2048+t][64]
//   [524288,  1048576)  k  bf16  [b*2048+t][64]
//   [1048576, 1572864)  vT bf16  [b][h][t]   (b*131072 + h*2048 + t)
//   [1572864, 1769472)  wT bf16  [sel][h][c] (sel*65536 + h*1024 + c)
//
// Round-5: single-variable attribution. Proj reverted to the proven 32-row
// baseline (round-4's 16-row split doubled grid-wide W-load traffic and
// risked spills under the 128-VGPR cap -> likely regressor). Attn keeps
// ONLY the T5 s_setprio change (positive prior on independent-wave attn,
// m191 +4-7%). Round-2 established ~73 us/iter fixed harness overhead
// (ws poison fill) -> kernel portion of baseline is ~46 us, ~30 of which
// is 3x launch overhead.

typedef __attribute__((ext_vector_type(8))) short short8;
typedef __attribute__((ext_vector_type(4))) float f32x4;

#define NTOT 524288   // 8192*64
#define WT_OFF (3 * NTOT)

__device__ __forceinline__ unsigned short f2bf(float f) {
    unsigned int u = __builtin_bit_cast(unsigned int, f);
    return (unsigned short)((u + 0x7fffu + ((u >> 16) & 1u)) >> 16);
}

__device__ __forceinline__ short8 pack8(float4 a, float4 b) {
    short8 r;
    r[0] = (short)f2bf(a.x); r[1] = (short)f2bf(a.y);
    r[2] = (short)f2bf(a.z); r[3] = (short)f2bf(a.w);
    r[4] = (short)f2bf(b.x); r[5] = (short)f2bf(b.y);
    r[6] = (short)f2bf(b.z); r[7] = (short)f2bf(b.w);
    return r;
}

// ---------------------------------------------------------------------------
// Kernel 1: transpose W (fp32 [1024][64]) -> wT bf16 [64][1024], x3 matrices
// (unchanged, proven)
// ---------------------------------------------------------------------------
__global__ __launch_bounds__(256) void wtrans_kernel(
    const float* __restrict__ Wq, const float* __restrict__ Wk,
    const float* __restrict__ Wv, unsigned short* __restrict__ wt)
{
    const int sel = blockIdx.x;
    const int c0  = blockIdx.y * 64;
    const float* W = (sel == 0) ? Wq : ((sel == 1) ? Wk : Wv);
    __shared__ unsigned short tile[64][72];
    const int tid = threadIdx.x;
    {
        const int c  = tid >> 2;
        const int hg = (tid & 3) * 16;
        const float* src = W + (size_t)(c0 + c) * 64 + hg;
        #pragma unroll
        for (int i = 0; i < 16; i++) tile[c][hg + i] = f2bf(src[i]);
    }
    __syncthreads();
    {
        const int h  = tid >> 2;
        const int cg = (tid & 3) * 16;
        unsigned short* dst = wt + ((size_t)sel * 64 + h) * 1024 + c0 + cg;
        #pragma unroll
        for (int i = 0; i < 16; i++) dst[i] = tile[cg + i][h];
    }
}

// ---------------------------------------------------------------------------
// Kernel 2: fused projections. 256 blocks x 512 threads (8 waves).
// Block covers 32 t-rows; wave w covers K in [w*128, (w+1)*128) -> 4 iters
// of (24 MFMA + 16 loads). Cross-wave reduction in 3 staged LDS phases
// (q, k, v) reusing one 67.6 KB buffer. (proven baseline body, unchanged)
// ---------------------------------------------------------------------------
__global__ __launch_bounds__(512) void proj_fused_kernel(
    const float* __restrict__ x, const unsigned short* __restrict__ wt,
    unsigned short* __restrict__ ws)
{
    const int m0   = blockIdx.x * 32;
    const int tid  = threadIdx.x;
    const int wave = tid >> 6, lane = tid & 63;   // wave 0..7
    const int quad = lane >> 4, l16 = lane & 15;

    const unsigned short* wq = wt;
    const unsigned short* wk = wt + 65536;
    const unsigned short* wv = wt + 131072;

    // shared scratch, reused per phase:
    //   q/k phases: [8][32][66] floats (idx (w*32+t)*66 + h)
    //   v phase:    [8][64][33] floats (idx (w*64+h)*33 + t)
    __shared__ float lds[16896];   // 67.6 KB

    f32x4 aq[2][4] = {}, ak[2][4] = {}, av[4][2] = {};

    const int kbase = wave * 128;
    const float* xrow0 = x + (size_t)(m0 + l16) * 1024 + kbase + quad * 8;
    const float* xrow1 = xrow0 + (size_t)16 * 1024;
    float4 xa0 = *(const float4*)(xrow0);
    float4 xb0 = *(const float4*)(xrow0 + 4);
    float4 xa1 = *(const float4*)(xrow1);
    float4 xb1 = *(const float4*)(xrow1 + 4);
    for (int kk = 0; kk < 128; kk += 32) {
        const int nk = (kk + 32) & 127;     // wraps on last iter (unused)
        float4 na0 = *(const float4*)(xrow0 + nk);
        float4 nb0 = *(const float4*)(xrow0 + nk + 4);
        float4 na1 = *(const float4*)(xrow1 + nk);
        float4 nb1 = *(const float4*)(xrow1 + nk + 4);
        short8 af0 = pack8(xa0, xb0);
        short8 af1 = pack8(xa1, xb1);
        const int wo = kbase + kk + quad * 8;
        #pragma unroll
        for (int nt = 0; nt < 4; nt++) {
            const size_t ro = (size_t)(nt * 16 + l16) * 1024 + wo;
            short8 bq = *(const short8*)(wq + ro);
            short8 bk = *(const short8*)(wk + ro);
            short8 bv = *(const short8*)(wv + ro);
            aq[0][nt] = __builtin_amdgcn_mfma_f32_16x16x32_bf16(af0, bq, aq[0][nt], 0, 0, 0);
            aq[1][nt] = __builtin_amdgcn_mfma_f32_16x16x32_bf16(af1, bq, aq[1][nt], 0, 0, 0);
            ak[0][nt] = __builtin_amdgcn_mfma_f32_16x16x32_bf16(af0, bk, ak[0][nt], 0, 0, 0);
            ak[1][nt] = __builtin_amdgcn_mfma_f32_16x16x32_bf16(af1, bk, ak[1][nt], 0, 0, 0);
            av[nt][0] = __builtin_amdgcn_mfma_f32_16x16x32_bf16(bv, af0, av[nt][0], 0, 0, 0);
            av[nt][1] = __builtin_amdgcn_mfma_f32_16x16x32_bf16(bv, af1, av[nt][1], 0, 0, 0);
        }
        xa0 = na0; xb0 = nb0; xa1 = na1; xb1 = nb1;
    }

    const int b   = m0 >> 11;
    const int tb0 = m0 & 2047;
    const int rrow = tid >> 4, rh0 = (tid & 15) * 4;   // q/k reduce mapping

    // ---- phase Q: stash, reduce 8-way, store ----
    #pragma unroll
    for (int tf = 0; tf < 2; tf++)
        #pragma unroll
        for (int nt = 0; nt < 4; nt++)
            #pragma unroll
            for (int r = 0; r < 4; r++)
                lds[(wave * 32 + tf * 16 + quad * 4 + r) * 66 + nt * 16 + l16]
                    = aq[tf][nt][r];
    __syncthreads();
    {
        float s[4] = {0.f, 0.f, 0.f, 0.f};
        #pragma unroll
        for (int w = 0; w < 8; w++)
            #pragma unroll
            for (int i = 0; i < 4; i++)
                s[i] += lds[(w * 32 + rrow) * 66 + rh0 + i];
        #pragma unroll
        for (int i = 0; i < 4; i++)
            ws[(size_t)(m0 + rrow) * 64 + rh0 + i] = f2bf(s[i]);
    }
    __syncthreads();

    // ---- phase K ----
    #pragma unroll
    for (int tf = 0; tf < 2; tf++)
        #pragma unroll
        for (int nt = 0; nt < 4; nt++)
            #pragma unroll
            for (int r = 0; r < 4; r++)
                lds[(wave * 32 + tf * 16 + quad * 4 + r) * 66 + nt * 16 + l16]
                    = ak[tf][nt][r];
    __syncthreads();
    {
        float s[4] = {0.f, 0.f, 0.f, 0.f};
        #pragma unroll
        for (int w = 0; w < 8; w++)
            #pragma unroll
            for (int i = 0; i < 4; i++)
                s[i] += lds[(w * 32 + rrow) * 66 + rh0 + i];
        #pragma unroll
        for (int i = 0; i < 4; i++)
            ws[NTOT + (size_t)(m0 + rrow) * 64 + rh0 + i] = f2bf(s[i]);
    }
    __syncthreads();

    // ---- phase V: av[nt][tf][r] -> h = nt*16+quad*4+r, t = tf*16+l16 ----
    #pragma unroll
    for (int nt = 0; nt < 4; nt++)
        #pragma unroll
        for (int tf = 0; tf < 2; tf++)
            #pragma unroll
            for (int r = 0; r < 4; r++)
                lds[(wave * 64 + nt * 16 + quad * 4 + r) * 33 + tf * 16 + l16]
                    = av[nt][tf][r];
    __syncthreads();
    {
        const int h = tid >> 3, t0 = (tid & 7) * 4;
        unsigned short* vdst = ws + 2 * NTOT + (size_t)b * 131072
                             + (size_t)h * 2048 + tb0;
        float s[4] = {0.f, 0.f, 0.f, 0.f};
        #pragma unroll
        for (int w = 0; w < 8; w++)
            #pragma unroll
            for (int i = 0; i < 4; i++)
                s[i] += lds[(w * 64 + h) * 33 + t0 + i];
        #pragma unroll
        for (int i = 0; i < 4; i++)
            vdst[t0 + i] = f2bf(s[i]);
    }
}

// ---------------------------------------------------------------------------
// Kernel 3: fused flash attention, 8-way in-block K-split + XCD swizzle.
// Baseline-proven body + s_setprio around the MFMA clusters (T5) -- the ONLY
// delta vs the 119.2 us baseline.
// ---------------------------------------------------------------------------
__global__ __launch_bounds__(512) void attn_fused_kernel(
    const unsigned short* __restrict__ ws, float* __restrict__ out)
{
    const int B    = blockIdx.x;
    const int xcd  = B & 7;
    const int slot = B >> 3;
    const int b    = xcd & 3;
    const int qt   = (slot << 1) | (xcd >> 2);   // 0..127
    const int q0 = qt * 16;
    const int tid  = threadIdx.x;
    const int wave = tid >> 6, lane = tid & 63;  // wave 0..7
    const int quad = lane >> 4, l16 = lane & 15;

    const unsigned short* Q  = ws + (size_t)b * 131072;
    const unsigned short* K  = ws + NTOT + (size_t)b * 131072;
    const unsigned short* VT = ws + 2 * NTOT + (size_t)b * 131072;

    __shared__ unsigned short p_lds[8][16][72];  // per-wave P scratch
    __shared__ float o_red[8][16][68];           // per-wave partial O
    __shared__ float ml_red[8][2][16];           // per-wave m / l

    const int qrow = q0 + l16;
    short8 qf0 = *(const short8*)(Q + (size_t)qrow * 64 + quad * 8);
    short8 qf1 = *(const short8*)(Q + (size_t)qrow * 64 + 32 + quad * 8);

    f32x4 o[4] = {};
    float m_i[4], l_i[4];
    #pragma unroll
    for (int r = 0; r < 4; r++) { m_i[r] = -1e30f; l_i[r] = 0.f; }

    const int qi = q0 + quad * 4;
    const int nkt = (qt >> 2) + 1;

    for (int t = wave; t < nkt; t += 8) {
        const int j0 = t * 64;
        f32x4 s[4] = {};
        __builtin_amdgcn_s_setprio(1);
        #pragma unroll
        for (int nt = 0; nt < 4; nt++) {
            const unsigned short* kp = K + (size_t)(j0 + nt * 16 + l16) * 64 + quad * 8;
            short8 kf0 = *(const short8*)(kp);
            short8 kf1 = *(const short8*)(kp + 32);
            s[nt] = __builtin_amdgcn_mfma_f32_16x16x32_bf16(qf0, kf0, s[nt], 0, 0, 0);
            s[nt] = __builtin_amdgcn_mfma_f32_16x16x32_bf16(qf1, kf1, s[nt], 0, 0, 0);
        }
        __builtin_amdgcn_s_setprio(0);
        float pm[4] = {-1e30f, -1e30f, -1e30f, -1e30f};
        #pragma unroll
        for (int nt = 0; nt < 4; nt++) {
            const int kj = j0 + nt * 16 + l16;
            #pragma unroll
            for (int r = 0; r < 4; r++) {
                float v = s[nt][r] * 0.125f;
                v = (kj > qi + r || v == 0.0f) ? -1e30f : v;  // causal + ==0 quirk
                s[nt][r] = v;
                pm[r] = fmaxf(pm[r], v);
            }
        }
        #pragma unroll
        for (int off = 1; off < 16; off <<= 1)
            #pragma unroll
            for (int r = 0; r < 4; r++)
                pm[r] = fmaxf(pm[r], __shfl_xor(pm[r], off));
        float alpha[4];
        #pragma unroll
        for (int r = 0; r < 4; r++) {
            float mn = fmaxf(m_i[r], pm[r]);
            alpha[r] = __expf(m_i[r] - mn);
            m_i[r] = mn;
        }
        float ps[4] = {0.f, 0.f, 0.f, 0.f};
        #pragma unroll
        for (int nt = 0; nt < 4; nt++)
            #pragma unroll
            for (int r = 0; r < 4; r++) {
                float p = __expf(s[nt][r] - m_i[r]);
                ps[r] += p;
                p_lds[wave][quad * 4 + r][nt * 16 + l16] = f2bf(p);
            }
        #pragma unroll
        for (int off = 1; off < 16; off <<= 1)
            #pragma unroll
            for (int r = 0; r < 4; r++)
                ps[r] += __shfl_xor(ps[r], off);
        #pragma unroll
        for (int r = 0; r < 4; r++) l_i[r] = l_i[r] * alpha[r] + ps[r];
        #pragma unroll
        for (int ht = 0; ht < 4; ht++)
            #pragma unroll
            for (int r = 0; r < 4; r++)
                o[ht][r] *= alpha[r];
        __builtin_amdgcn_s_setprio(1);
        #pragma unroll
        for (int ks = 0; ks < 2; ks++) {
            short8 pf = *(const short8*)&p_lds[wave][l16][ks * 32 + quad * 8];
            #pragma unroll
            for (int ht = 0; ht < 4; ht++) {
                short8 vf = *(const short8*)(VT + (size_t)(ht * 16 + l16) * 2048 + j0 + ks * 32 + quad * 8);
                o[ht] = __builtin_amdgcn_mfma_f32_16x16x32_bf16(pf, vf, o[ht], 0, 0, 0);
            }
        }
        __builtin_amdgcn_s_setprio(0);
    }

    // ---- stash per-wave partial state ----
    #pragma unroll
    for (int ht = 0; ht < 4; ht++)
        #pragma unroll
        for (int r = 0; r < 4; r++)
            o_red[wave][quad * 4 + r][ht * 16 + l16] = o[ht][r];
    if (l16 == 0) {
        #pragma unroll
        for (int r = 0; r < 4; r++) {
            ml_red[wave][0][quad * 4 + r] = m_i[r];
            ml_red[wave][1][quad * 4 + r] = l_i[r];
        }
    }
    __syncthreads();

    // ---- 8-way combine: thread -> (row = tid>>5, col0 = (tid&31)*2) ----
    const int row = tid >> 5, c0 = (tid & 31) * 2;
    float M = -1e30f;
    #pragma unroll
    for (int w = 0; w < 8; w++) M = fmaxf(M, ml_red[w][0][row]);
    float wgt[8];
    float l = 0.f;
    #pragma unroll
    for (int w = 0; w < 8; w++) {
        wgt[w] = __expf(ml_red[w][0][row] - M);
        l += wgt[w] * ml_red[w][1][row];
    }
    const float inv = 1.0f / l;
    float* op = out + ((size_t)b * 2048 + q0 + row) * 64 + c0;
    #pragma unroll
    for (int i = 0; i < 2; i++) {
        const int col = c0 + i;
        float sv = 0.f;
        #pragma unroll
        for (int w = 0; w < 8; w++) sv += wgt[w] * o_red[w][row][col];
        op[i] = sv * inv;
    }
}

// ---------------------------------------------------------------------------
extern "C" void kernel_launch(void* const* d_in, const int* in_sizes, int n_in,
                              void* d_out, int out_size, void* d_ws, size_t ws_size,
                              hipStream_t stream) {
    const float* x  = (const float*)d_in[0];
    const float* Wq = (const float*)d_in[1];
    const float* Wk = (const float*)d_in[2];
    const float* Wv = (const float*)d_in[3];
    float* out = (float*)d_out;
    unsigned short* ws = (unsigned short*)d_ws;
    unsigned short* wT = ws + WT_OFF;

    wtrans_kernel<<<dim3(3, 16), 256, 0, stream>>>(Wq, Wk, Wv, wT);
    proj_fused_kernel<<<dim3(256), 512, 0, stream>>>(x, wT, ws);
    attn_fused_kernel<<<dim3(512), 512, 0, stream>>>(ws, out);
}